// Round 10
// baseline (675.391 us; speedup 1.0000x reference)
//
#include <hip/hip_runtime.h>

// Guided filter r=5, B=8 C=3 H=W=512 fp32 — persistent fused kernel, round 16.
// Grid = 1024 blocks (exactly 4/CU), each block processes 6 tiles:
// t = gid + 1024k -> SAME spatial tile (bx,by), plane advances by 4 each
// iteration. All spatial addressing / interior flags / thread roles are
// LOOP-INVARIANT; only base pointers advance (+4*512*512 per iter).
// Cross-tile software pipeline: next plane's P1 loads (38 floats) are issued
// immediately after the current P1-compute consumes xv/yv — HBM/L2 latency
// hides under the current tile's P2a..P4 instead of being exposed at tile
// start. Also removes 5 of 6 launch/drain rounds.
// Per-tile body = r13's proven structure (best: 42.5 us) + r14's P1 product
// stash; P4 = r13's 128-thread form (r14's pair-split raised conflicts):
//  - P1: 3 segs 9/9/8 (252 thr), 19-row register window (single 38-load
//    batch; r11 lesson: keep live loads <= ~40 floats), runtime row mask
//    (no intra-wave body duplication; r12 lesson), trailing-product stash.
//  - P2a/P2b: single body, runtime i<nout per-lane mask; INTR template
//    split only on block-uniform `interior`.
//  - P3: 2 segs x 8 rows. P4: 128 thr x 8 outputs, affine b64 reads,
//    x prefetched 2 phases ahead (current plane).
// All LDS accesses affine (chunk starts multiple of 8: PB(c0+d)=PB(c0)+OFFD(d)).
// Barriers per tile: P1|P2a|P2b|P3 + loop-end drain (next P1 writes v4
// which overlaps vab read by P4). LDS 40,352 B -> 4 blocks/CU.
// ab2 @0 (aliases v4 after P2a drain), vab @17,280 (=135*128).

#define R    5
#define TX   64
#define TY   16
#define IMG  512
#define AROWS (TY + 2 * R)   // 26
#define ACOLS (TX + 2 * R)   // 74
#define XCOLS (TX + 4 * R)   // 84
#define V4STR 97             // float4 row stride
#define ABSTR 83             // float2 row stride
#define OFF_VAB 17280                            // 135*128 >= ab2's 17,264
#define SMEM_TOTAL (AROWS * V4STR * 16)          // 40,352

#define PB(c)   ((c) + ((c) >> 3))
#define OFFD(d) ((d) + ((d) >> 3))   // PB(c0+d)-PB(c0) when c0%8==0

__device__ __forceinline__ float ccnt(int g) {
    int lo = max(g - R, 0), hi = min(g + R, IMG - 1);
    return (float)(hi - lo + 1);
}

// P1 load: 19 rows x (x,y) into registers. path 0: contiguous fast
// (interior, or boundary thread fully in-bounds); path 1: column OOB ->
// zeros; path 2: per-row masked. path/soff are loop-invariant.
__device__ __forceinline__ void p1_load(const float* __restrict__ xq,
                                        const float* __restrict__ yq,
                                        int path, size_t soff, int gy0, int gx,
                                        float (&xv)[19], float (&yv)[19]) {
    if (path == 0) {
        const float* xc = xq + soff;
        const float* yc = yq + soff;
#pragma unroll
        for (int j = 0; j < 19; ++j) {
            xv[j] = xc[(size_t)j * IMG];
            yv[j] = yc[(size_t)j * IMG];
        }
    } else if (path == 1) {
#pragma unroll
        for (int j = 0; j < 19; ++j) { xv[j] = 0.f; yv[j] = 0.f; }
    } else {
        const bool xok = ((unsigned)gx < (unsigned)IMG);
#pragma unroll
        for (int j = 0; j < 19; ++j) {
            int gy = gy0 + j;
            bool ok = xok && ((unsigned)gy < (unsigned)IMG);
            size_t o = (size_t)gy * IMG + gx;
            xv[j] = ok ? xq[o] : 0.f;
            yv[j] = ok ? yq[o] : 0.f;
        }
    }
}

// P2a inner: horizontal 11-sum ring + A,b math. Single body, runtime nout
// (per-lane mask — NO divergent body duplication). INTR is block-uniform.
template <bool INTR>
__device__ __forceinline__ void p2_body(const float4* __restrict__ bp,
                                        float2* pres, int nout, int ax0,
                                        float cy, bool ayok) {
    float4 ring[10];
#pragma unroll
    for (int d = 0; d < 10; ++d) ring[d] = bp[OFFD(d)];
    float sx = 0.f, sy = 0.f, sxy = 0.f, sxx = 0.f;
#pragma unroll
    for (int d = 0; d < 10; ++d) {
        sx += ring[d].x; sy += ring[d].y;
        sxy += ring[d].z; sxx += ring[d].w;
    }
#pragma unroll
    for (int i = 0; i < 10; ++i) {
        if (i < nout) {
            float4 lead = bp[OFFD(10 + i)];
            sx += lead.x; sy += lead.y; sxy += lead.z; sxx += lead.w;
            if (i > 0) {
                float4 o = ring[i - 1];
                sx -= o.x; sy -= o.y; sxy -= o.z; sxx -= o.w;
            }
            float A = 0.f, bb = 0.f;
            if (INTR) {
                const float inv = 1.0f / 121.0f;
                float mx = sx * inv, my = sy * inv;
                float cov = sxy * inv - mx * my;
                float var = sxx * inv - mx * mx;
                A = cov * __builtin_amdgcn_rcpf(var + 0.01f);
                bb = my - A * mx;
            } else {
                const int ax = ax0 + i;
                if (ayok && ((unsigned)ax < (unsigned)IMG)) {
                    float inv = __builtin_amdgcn_rcpf(cy * ccnt(ax));
                    float mx = sx * inv, my = sy * inv;
                    float cov = sxy * inv - mx * my;
                    float var = sxx * inv - mx * mx;
                    A = cov * __builtin_amdgcn_rcpf(var + 0.01f);
                    bb = my - A * mx;
                }
            }
            pres[i] = make_float2(A, bb);
        }
    }
}

__global__ __launch_bounds__(256, 4) void guided_fused(
        const float* __restrict__ x, const float* __restrict__ y,
        float* __restrict__ out, int nplanes) {
    __shared__ __align__(16) unsigned char smem[SMEM_TOTAL];
    float4 (*v4)[V4STR] = (float4(*)[V4STR])smem;
    float2 (*ab2)[ABSTR] = (float2(*)[ABSTR])smem;              // aliases v4
    float2 (*vab)[ABSTR] = (float2(*)[ABSTR])(smem + OFF_VAB);  // disjoint from ab2

    const int tid = threadIdx.x;
    const int gid = blockIdx.x;             // 0..1023
    const int bx = gid & 7;
    const int by = (gid >> 3) & 31;
    const int p0 = gid >> 8;                // 0..3
    const int tx0 = bx * TX;
    const int ty0 = by * TY;
    const size_t NPIX = (size_t)IMG * IMG;
    const bool interior = (tx0 >= 2 * R) && (tx0 + TX + 2 * R - 1 < IMG) &&
                          (ty0 >= 2 * R) && (ty0 + TY + 2 * R - 1 < IMG);

    // ---- Loop-invariant P1 roles (252 threads: 3 segs of 9/9/8 rows).
    const bool p1on = tid < 3 * XCOLS;
    const int seg = tid / XCOLS;
    const int cc  = tid - seg * XCOLS;
    const int r0  = seg * 9;                // 0, 9, 18
    const int gx  = tx0 - 2 * R + cc;
    const int gy0 = ty0 - 2 * R + r0;
    const bool xok = ((unsigned)gx < (unsigned)IMG);
    const bool rows_ok = (gy0 >= 0) && (gy0 + 18 < IMG);
    int path = 2;
    if (interior || (rows_ok && xok)) path = 0;
    else if (rows_ok) path = 1;
    const size_t soff = (path == 0) ? ((size_t)gy0 * IMG + gx) : 0;
    float4* const wp1 = &v4[r0][PB(cc)];

    // ---- Loop-invariant P2 roles (234 threads).
    const bool p2on = tid < 9 * AROWS;
    const int p2ch = tid / AROWS;
    const int p2r  = tid - p2ch * AROWS;
    const int p2nout = (p2ch == 8) ? 10 : 8;
    const int p2pb0  = 9 * p2ch;
    const float4* const p2bp = &v4[p2r][p2pb0];
    float2* const p2bw = &ab2[p2r][p2pb0];
    const int ay = ty0 - R + p2r;
    const float p2cy = ccnt(ay);
    const bool ayok = ((unsigned)ay < (unsigned)IMG);
    const int ax0 = tx0 - R + 8 * p2ch;

    // ---- Loop-invariant P3 roles (148 threads).
    const bool p3on = tid < 2 * ACOLS;
    const int p3seg = (tid >= ACOLS) ? 1 : 0;
    const int p3ac = tid - p3seg * ACOLS;
    const int p3r0 = p3seg * 8;
    const float2* const p3rp = &ab2[p3r0][PB(p3ac)];
    float2* const p3wp = &vab[p3r0][PB(p3ac)];

    // ---- Loop-invariant P4 roles (128 threads).
    const bool p4on = tid < TY * 8;
    const int p4oy = tid >> 3;
    const int p4ch = tid & 7;
    const int p4c0 = 8 * p4ch;
    const float2* const p4vb = &vab[p4oy][9 * p4ch];   // PB(8ch) = 9ch
    const size_t obase_sp = (size_t)(ty0 + p4oy) * IMG + tx0 + p4c0;
    const int p4gy = ty0 + p4oy;
    const float p4cy = ccnt(p4gy);

    // ---- Per-plane base pointers (advance by 4 planes per iteration).
    const float* xb = x + (size_t)p0 * NPIX;
    const float* yb = y + (size_t)p0 * NPIX;
    float* ob = out + (size_t)p0 * NPIX;

    float xv[19], yv[19];
    if (p1on) p1_load(xb, yb, path, soff, gy0, gx, xv, yv);

#pragma unroll 1
    for (int pl = p0; pl < nplanes; pl += 4) {
        // ---- P1-compute: vertical 11-sums from registers -> v4.
        if (p1on) {
            float sx = 0.f, sy = 0.f, sxy = 0.f, sxx = 0.f;
            float pxy[8], pxx[8];   // trailing-edge product stash
#pragma unroll
            for (int j = 0; j < 11; ++j) {
                float mxy = xv[j] * yv[j];
                float mxx = xv[j] * xv[j];
                sx += xv[j]; sy += yv[j];
                sxy += mxy; sxx += mxx;
                if (j < 8) { pxy[j] = mxy; pxx[j] = mxx; }
            }
            wp1[0] = make_float4(sx, sy, sxy, sxx);
#pragma unroll
            for (int s = 1; s < 9; ++s) {
                if (r0 + s < AROWS) {   // seg2 stops at 8 rows
                    float xn = xv[s + 10], yn = yv[s + 10];
                    sx  += xn - xv[s - 1];
                    sy  += yn - yv[s - 1];
                    sxy += xn * yn - pxy[s - 1];
                    sxx += xn * xn - pxx[s - 1];
                    wp1[(size_t)s * V4STR] = make_float4(sx, sy, sxy, sxx);
                }
            }
        }
        // ---- Issue NEXT plane's loads now (xv/yv consumed above): the
        // HBM/L2 latency hides under this tile's P2a..P4.
        const bool more = (pl + 4) < nplanes;
        if (more && p1on)
            p1_load(xb + 4 * NPIX, yb + 4 * NPIX, path, soff, gy0, gx, xv, yv);
        __syncthreads();

        // ---- P2a: horizontal 11-sums -> A,b DEFERRED to registers.
        float2 pres[10];
        if (p2on) {
            if (interior) p2_body<true >(p2bp, pres, p2nout, ax0, p2cy, ayok);
            else          p2_body<false>(p2bp, pres, p2nout, ax0, p2cy, ayok);
        }
        __syncthreads();   // v4 reads drained -> safe to overwrite with ab2

        // ---- x-prefetch for P4 (current plane; 2 phases ahead).
        float4 xpa, xpb;
        if (p4on) {
            xpa = *reinterpret_cast<const float4*>(&xb[obase_sp]);
            xpb = *reinterpret_cast<const float4*>(&xb[obase_sp + 4]);
        }

        // ---- P2b: write deferred A,b into ab2 (aliases v4). Affine.
        if (p2on) {
#pragma unroll
            for (int i = 0; i < 10; ++i) {
                if (i < p2nout) p2bw[OFFD(i)] = pres[i];
            }
        }
        __syncthreads();

        // ---- P3: vertical 11-sums of (A,b): 74 cols x 2 segs of 8 rows.
        if (p3on) {
            float2 ring[10];
#pragma unroll
            for (int d = 0; d < 10; ++d) ring[d] = p3rp[(size_t)d * ABSTR];
            float sa = 0.f, sb = 0.f;
#pragma unroll
            for (int d = 0; d < 10; ++d) { sa += ring[d].x; sb += ring[d].y; }
#pragma unroll
            for (int s = 0; s < 8; ++s) {
                float2 lead = p3rp[(size_t)(10 + s) * ABSTR];
                sa += lead.x; sb += lead.y;
                if (s > 0) {
                    float2 o = ring[s - 1];
                    sa -= o.x; sb -= o.y;
                }
                p3wp[(size_t)s * ABSTR] = make_float2(sa, sb);
            }
        }
        __syncthreads();

        // ---- P4: horizontal 11-sums + epilogue. 128 thr x 8 outputs.
        if (p4on) {
            float2 ring[10];
#pragma unroll
            for (int d = 0; d < 10; ++d) ring[d] = p4vb[OFFD(d)];
            float sa = 0.f, sb = 0.f;
#pragma unroll
            for (int d = 0; d < 10; ++d) { sa += ring[d].x; sb += ring[d].y; }
            const float xvv[8] = {xpa.x, xpa.y, xpa.z, xpa.w,
                                  xpb.x, xpb.y, xpb.z, xpb.w};
            float res[8];
            if (interior) {
#pragma unroll
                for (int i = 0; i < 8; ++i) {
                    float2 lead = p4vb[OFFD(10 + i)];
                    sa += lead.x; sb += lead.y;
                    if (i > 0) {
                        float2 o = ring[i - 1];
                        sa -= o.x; sb -= o.y;
                    }
                    const float inv = 1.0f / 121.0f;
                    res[i] = (sa * inv) * xvv[i] + (sb * inv);
                }
            } else {
#pragma unroll
                for (int i = 0; i < 8; ++i) {
                    float2 lead = p4vb[OFFD(10 + i)];
                    sa += lead.x; sb += lead.y;
                    if (i > 0) {
                        float2 o = ring[i - 1];
                        sa -= o.x; sb -= o.y;
                    }
                    float inv = __builtin_amdgcn_rcpf(p4cy * ccnt(tx0 + p4c0 + i));
                    res[i] = (sa * inv) * xvv[i] + (sb * inv);
                }
            }
            *reinterpret_cast<float4*>(&ob[obase_sp]) =
                make_float4(res[0], res[1], res[2], res[3]);
            *reinterpret_cast<float4*>(&ob[obase_sp + 4]) =
                make_float4(res[4], res[5], res[6], res[7]);
        }
        __syncthreads();   // vab reads drained before next tile's P1 writes

        xb += 4 * NPIX; yb += 4 * NPIX; ob += 4 * NPIX;
    }
}

extern "C" void kernel_launch(void* const* d_in, const int* in_sizes, int n_in,
                              void* d_out, int out_size, void* d_ws, size_t ws_size,
                              hipStream_t stream) {
    const float* x = (const float*)d_in[0];
    const float* y = (const float*)d_in[1];
    float* out = (float*)d_out;

    const int planes = in_sizes[0] / (IMG * IMG);  // 24

    dim3 grid(1024);   // 4 persistent blocks per CU; tile (bx,by) fixed,
                       // plane strides by 4 inside the kernel loop.
    guided_fused<<<grid, 256, 0, stream>>>(x, y, out, planes);
}

// Round 11
// 116.730 us; speedup vs baseline: 5.7859x; 5.7859x over previous
//
#include <hip/hip_runtime.h>

// Guided filter r=5, B=8 C=3 H=W=512 fp32 — single fused kernel, round 17.
// = r13 (confirmed best structure: 42.5 us) + 2 micro-edits:
//  (1) P1 trailing-product stash: pxy[8]/pxx[8] saved during prime (muls
//      CSE'd), update rows reuse them: -16 mul/thread in the largest phase.
//  (2) x-prefetch hoisted to directly after the P1 barrier (before P2a):
//      P4's two float4 x-loads get P2a+P2b+P3 of latency cover (was P2b+P3).
// Structure-space map (falsified, do not revisit):
//  - r11/r15: bigger tiles / fewer threads -> cross-block overlap loss and
//    VGPR load-batch overflow beat the work savings.
//  - r12: intra-wave divergent template bodies -> straggler wave at barrier.
//  - r14: P4 pair-split -> conflict rise, no win.
//  - r16: persistent blocks + cross-tile register pipeline -> scratch spill
//    (WRITE_SIZE 24.5 MB -> 1.25 GB). NO long-lived regs across barriers.
// Structure: TY=16, grid 8x32x24 = 6144 blocks, 256 thr, LDS 40,352 B
// -> 4 blocks/CU. All LDS accesses affine (chunk starts multiple of 8:
// PB(c0+d) = PB(c0) + OFFD(d), compile-time immediates).
// Pipeline: P1 vsums(x,y,xy,xx)->v4[26][97sw] f4 | x-prefetch (128 thr) |
//   P2a hsums+A,b->regs | P2b regs->ab2 (ALIASES v4, @0) | P3 vsums(A,b)
//   2 segs x 8 rows -> vab @17,280 | P4 hsums+epilogue (128 thr x 8 out),
//   2x float4 stores.
// Bank floors: measured SQ_LDS_BANK_CONFLICT is the multi-word access floor
// (b128 8 words/bank, b64 4/bank), not fixable conflicts.

#define R    5
#define TX   64
#define TY   16
#define IMG  512
#define AROWS (TY + 2 * R)   // 26
#define ACOLS (TX + 2 * R)   // 74
#define XCOLS (TX + 4 * R)   // 84
#define V4STR 97             // float4 row stride
#define ABSTR 83             // float2 row stride
#define OFF_VAB 17280                            // 135*128 >= ab2's 17,264
#define SMEM_TOTAL (AROWS * V4STR * 16)          // 40,352

#define PB(c)   ((c) + ((c) >> 3))
#define OFFD(d) ((d) + ((d) >> 3))   // PB(c0+d)-PB(c0) when c0%8==0

__device__ __forceinline__ float ccnt(int g) {
    int lo = max(g - R, 0), hi = min(g + R, IMG - 1);
    return (float)(hi - lo + 1);
}

// P2a inner: horizontal 11-sum ring + A,b math. Single body, runtime nout
// (per-lane mask — NO divergent body duplication). INTR is block-uniform.
template <bool INTR>
__device__ __forceinline__ void p2_body(const float4* __restrict__ bp,
                                        float2* pres, int nout, int ax0,
                                        float cy, bool ayok) {
    float4 ring[10];
#pragma unroll
    for (int d = 0; d < 10; ++d) ring[d] = bp[OFFD(d)];
    float sx = 0.f, sy = 0.f, sxy = 0.f, sxx = 0.f;
#pragma unroll
    for (int d = 0; d < 10; ++d) {
        sx += ring[d].x; sy += ring[d].y;
        sxy += ring[d].z; sxx += ring[d].w;
    }
#pragma unroll
    for (int i = 0; i < 10; ++i) {
        if (i < nout) {
            float4 lead = bp[OFFD(10 + i)];
            sx += lead.x; sy += lead.y; sxy += lead.z; sxx += lead.w;
            if (i > 0) {
                float4 o = ring[i - 1];
                sx -= o.x; sy -= o.y; sxy -= o.z; sxx -= o.w;
            }
            float A = 0.f, bb = 0.f;
            if (INTR) {
                const float inv = 1.0f / 121.0f;
                float mx = sx * inv, my = sy * inv;
                float cov = sxy * inv - mx * my;
                float var = sxx * inv - mx * mx;
                A = cov * __builtin_amdgcn_rcpf(var + 0.01f);
                bb = my - A * mx;
            } else {
                const int ax = ax0 + i;
                if (ayok && ((unsigned)ax < (unsigned)IMG)) {
                    float inv = __builtin_amdgcn_rcpf(cy * ccnt(ax));
                    float mx = sx * inv, my = sy * inv;
                    float cov = sxy * inv - mx * my;
                    float var = sxx * inv - mx * mx;
                    A = cov * __builtin_amdgcn_rcpf(var + 0.01f);
                    bb = my - A * mx;
                }
            }
            pres[i] = make_float2(A, bb);
        }
    }
}

__global__ __launch_bounds__(256, 4) void guided_fused(
        const float* __restrict__ x, const float* __restrict__ y,
        float* __restrict__ out) {
    __shared__ __align__(16) unsigned char smem[SMEM_TOTAL];
    float4 (*v4)[V4STR] = (float4(*)[V4STR])smem;
    float2 (*ab2)[ABSTR] = (float2(*)[ABSTR])smem;              // aliases v4
    float2 (*vab)[ABSTR] = (float2(*)[ABSTR])(smem + OFF_VAB);  // disjoint from ab2

    const int plane = blockIdx.z;
    const int tx0 = blockIdx.x * TX;
    const int ty0 = blockIdx.y * TY;
    const int tid = threadIdx.x;
    const size_t pbase = (size_t)plane * IMG * IMG;
    const float* xp = x + pbase;
    const float* yp = y + pbase;
    const bool interior = (tx0 >= 2 * R) && (tx0 + TX + 2 * R - 1 < IMG) &&
                          (ty0 >= 2 * R) && (ty0 + TY + 2 * R - 1 < IMG);

    // ---- P1: vertical 11-sums at 84 cols x 26 A,b-rows. 3 segs (9/9/8).
    // 19-row register window: all 38 loads issue in one batch (VGPR-sized).
    if (tid < 3 * XCOLS) {
        const int seg = tid / XCOLS;
        const int cc  = tid - seg * XCOLS;
        const int r0  = seg * 9;              // 0, 9, 18
        const int gx  = tx0 - 2 * R + cc;
        const int gy0 = ty0 - 2 * R + r0;

        float xv[19], yv[19];
        if (interior) {
            const float* xc = xp + (size_t)gy0 * IMG + gx;
            const float* yc = yp + (size_t)gy0 * IMG + gx;
#pragma unroll
            for (int j = 0; j < 19; ++j) {
                xv[j] = xc[(size_t)j * IMG];
                yv[j] = yc[(size_t)j * IMG];
            }
        } else {
            const bool xok = ((unsigned)gx < (unsigned)IMG);
            const bool rows_ok = (gy0 >= 0) && (gy0 + 18 < IMG);
            if (rows_ok) {
                if (xok) {
                    const float* xc = xp + (size_t)gy0 * IMG + gx;
                    const float* yc = yp + (size_t)gy0 * IMG + gx;
#pragma unroll
                    for (int j = 0; j < 19; ++j) {
                        xv[j] = xc[(size_t)j * IMG];
                        yv[j] = yc[(size_t)j * IMG];
                    }
                } else {
#pragma unroll
                    for (int j = 0; j < 19; ++j) { xv[j] = 0.f; yv[j] = 0.f; }
                }
            } else {
#pragma unroll
                for (int j = 0; j < 19; ++j) {
                    int gy = gy0 + j;
                    bool ok = xok && ((unsigned)gy < (unsigned)IMG);
                    size_t o = (size_t)gy * IMG + gx;
                    xv[j] = ok ? xp[o] : 0.f;
                    yv[j] = ok ? yp[o] : 0.f;
                }
            }
        }
        float sx = 0.f, sy = 0.f, sxy = 0.f, sxx = 0.f;
        float pxy[8], pxx[8];   // trailing-edge product stash (rows 0..7)
#pragma unroll
        for (int j = 0; j < 11; ++j) {
            float mxy = xv[j] * yv[j];
            float mxx = xv[j] * xv[j];
            sx += xv[j]; sy += yv[j];
            sxy += mxy; sxx += mxx;
            if (j < 8) { pxy[j] = mxy; pxx[j] = mxx; }
        }
        float4* wp = &v4[r0][PB(cc)];
        wp[0] = make_float4(sx, sy, sxy, sxx);
#pragma unroll
        for (int s = 1; s < 9; ++s) {
            if (r0 + s < AROWS) {   // seg2 stops at 8 rows
                float xn = xv[s + 10], yn = yv[s + 10];
                sx  += xn - xv[s - 1];
                sy  += yn - yv[s - 1];
                sxy += xn * yn - pxy[s - 1];
                sxx += xn * xn - pxx[s - 1];
                wp[(size_t)s * V4STR] = make_float4(sx, sy, sxy, sxx);
            }
        }
    }
    __syncthreads();

    // ---- x-prefetch for P4, hoisted BEFORE P2a: the two float4 loads get
    // P2a+P2b+P3 of latency cover. 8 VGPRs live across P2a (LDS is the
    // binding occupancy resource, not VGPR — safe).
    float4 xpa = make_float4(0.f, 0.f, 0.f, 0.f), xpb = xpa;
    size_t obase = 0;
    if (tid < TY * 8) {
        const int oy = tid >> 3;
        const int ch = tid & 7;
        obase = (size_t)(ty0 + oy) * IMG + tx0 + 8 * ch;
        xpa = *reinterpret_cast<const float4*>(&xp[obase]);
        xpb = *reinterpret_cast<const float4*>(&xp[obase + 4]);
    }

    // ---- P2a: horizontal 11-sums -> A,b on 74x26, DEFERRED to registers.
    // 234 threads: chunk ch = tid/26 (0..8), row r = tid%26, c0 = 8ch.
    // Runtime nout (8, or 10 for ch=8) masked per-lane inside ONE body.
    int p2_r = 0, p2_pb0 = 0, p2_nout = 0;
    float2 pres[10];
    if (tid < 9 * AROWS) {
        const int ch = tid / AROWS;
        const int r  = tid - ch * AROWS;
        const int nout = (ch == 8) ? 10 : 8;
        p2_r = r; p2_pb0 = 9 * ch; p2_nout = nout;
        const float4* bp = &v4[r][p2_pb0];
        const int ay = ty0 - R + r;
        const float cy = ccnt(ay);
        const bool ayok = ((unsigned)ay < (unsigned)IMG);
        const int ax0 = tx0 - R + 8 * ch;
        if (interior) p2_body<true >(bp, pres, nout, ax0, cy, ayok);
        else          p2_body<false>(bp, pres, nout, ax0, cy, ayok);
    }
    __syncthreads();   // all v4 reads drained -> safe to overwrite with ab2

    // ---- P2b: write deferred A,b into ab2 (aliases v4 region). Affine,
    // single loop with runtime mask (no divergent duplication).
    if (tid < 9 * AROWS) {
        float2* bw = &ab2[p2_r][p2_pb0];
#pragma unroll
        for (int i = 0; i < 10; ++i) {
            if (i < p2_nout) bw[OFFD(i)] = pres[i];
        }
    }
    __syncthreads();

    // ---- P3: vertical 11-sums of (A,b): 74 cols x 2 segs of 8 rows. Ring.
    if (tid < 2 * ACOLS) {
        const int seg = (tid >= ACOLS) ? 1 : 0;
        const int ac = tid - seg * ACOLS;
        const int r0 = seg * 8;
        const float2* rp = &ab2[r0][PB(ac)];
        float2* wp = &vab[r0][PB(ac)];
        float2 ring[10];
#pragma unroll
        for (int d = 0; d < 10; ++d) ring[d] = rp[(size_t)d * ABSTR];
        float sa = 0.f, sb = 0.f;
#pragma unroll
        for (int d = 0; d < 10; ++d) { sa += ring[d].x; sb += ring[d].y; }
#pragma unroll
        for (int s = 0; s < 8; ++s) {
            float2 lead = rp[(size_t)(10 + s) * ABSTR];
            sa += lead.x; sb += lead.y;
            if (s > 0) {
                float2 o = ring[s - 1];
                sa -= o.x; sb -= o.y;
            }
            wp[(size_t)s * ABSTR] = make_float2(sa, sb);
        }
    }
    __syncthreads();

    // ---- P4: horizontal 11-sums + epilogue. 16 rows x 8 width-8 chunks,
    // 128 threads, 8 outputs each. Affine b64 reads; prefetched x.
    if (tid < TY * 8) {
        const int oy = tid >> 3;
        const int ch = tid & 7;
        const int c0 = 8 * ch;
        const float2* vb = &vab[oy][9 * ch];   // PB(8ch) = 9ch
        float2 ring[10];
#pragma unroll
        for (int d = 0; d < 10; ++d) ring[d] = vb[OFFD(d)];
        float sa = 0.f, sb = 0.f;
#pragma unroll
        for (int d = 0; d < 10; ++d) { sa += ring[d].x; sb += ring[d].y; }
        const float xv[8] = {xpa.x, xpa.y, xpa.z, xpa.w,
                             xpb.x, xpb.y, xpb.z, xpb.w};
        float res[8];
        if (interior) {
#pragma unroll
            for (int i = 0; i < 8; ++i) {
                float2 lead = vb[OFFD(10 + i)];
                sa += lead.x; sb += lead.y;
                if (i > 0) {
                    float2 o = ring[i - 1];
                    sa -= o.x; sb -= o.y;
                }
                const float inv = 1.0f / 121.0f;
                res[i] = (sa * inv) * xv[i] + (sb * inv);
            }
        } else {
            const int gy = ty0 + oy;
            const float cy = ccnt(gy);
#pragma unroll
            for (int i = 0; i < 8; ++i) {
                float2 lead = vb[OFFD(10 + i)];
                sa += lead.x; sb += lead.y;
                if (i > 0) {
                    float2 o = ring[i - 1];
                    sa -= o.x; sb -= o.y;
                }
                float inv = __builtin_amdgcn_rcpf(cy * ccnt(tx0 + c0 + i));
                res[i] = (sa * inv) * xv[i] + (sb * inv);
            }
        }
        *reinterpret_cast<float4*>(&out[pbase + obase]) =
            make_float4(res[0], res[1], res[2], res[3]);
        *reinterpret_cast<float4*>(&out[pbase + obase + 4]) =
            make_float4(res[4], res[5], res[6], res[7]);
    }
}

extern "C" void kernel_launch(void* const* d_in, const int* in_sizes, int n_in,
                              void* d_out, int out_size, void* d_ws, size_t ws_size,
                              hipStream_t stream) {
    const float* x = (const float*)d_in[0];
    const float* y = (const float*)d_in[1];
    float* out = (float*)d_out;

    const int planes = in_sizes[0] / (IMG * IMG);  // 24

    dim3 grid(IMG / TX, IMG / TY, planes);  // 8 x 32 x 24
    guided_fused<<<grid, 256, 0, stream>>>(x, y, out);
}